// Round 1
// baseline (263.794 us; speedup 1.0000x reference)
//
#include <hip/hip_runtime.h>
#include <math.h>

#define Bv   8192
#define EPSv 1e-5f
#define CONFv 0.1f

__device__ __forceinline__ float wave_sum64(float v){
  #pragma unroll
  for (int o = 32; o; o >>= 1) v += __shfl_xor(v, o, 64);
  return v;
}

// ---------------- kernel 0: zero the per-expert counters ----------------
__global__ void k_zero(int* __restrict__ cnt){
  if (threadIdx.x < 64) cnt[threadIdx.x] = 0;
}

// ---------------- kernel 1: h = relu(LN(X @ W1 + b1)) : 8192x128 -> 8192x256
__global__ __launch_bounds__(256) void k_rp1(const float* __restrict__ X,
    const float* __restrict__ W, const float* __restrict__ bias,
    const float* __restrict__ g, const float* __restrict__ beta,
    float* __restrict__ out)
{
  __shared__ float xs[8][128];
  __shared__ float hs[8][256];
  const int tid = threadIdx.x;
  const int r0  = blockIdx.x * 8;
  for (int i = tid; i < 8*32; i += 256){            // float4 staging
    int r = i >> 5, c = i & 31;
    ((float4*)xs[r])[c] = ((const float4*)X)[(size_t)(r0 + r)*32 + c];
  }
  __syncthreads();
  const int col = tid;
  float acc[8];
  #pragma unroll
  for (int r = 0; r < 8; r++) acc[r] = bias[col];
  for (int k = 0; k < 128; k += 4){
    float w0 = W[(k+0)*256+col], w1 = W[(k+1)*256+col];
    float w2 = W[(k+2)*256+col], w3 = W[(k+3)*256+col];
    #pragma unroll
    for (int r = 0; r < 8; r++){
      float4 x4 = *(const float4*)&xs[r][k];
      acc[r] += x4.x*w0 + x4.y*w1 + x4.z*w2 + x4.w*w3;
    }
  }
  #pragma unroll
  for (int r = 0; r < 8; r++) hs[r][col] = acc[r];
  __syncthreads();
  const int wave = tid >> 6, lane = tid & 63;
  #pragma unroll
  for (int rr = 0; rr < 2; rr++){
    int r = wave*2 + rr;
    float s = 0.f;
    #pragma unroll
    for (int j = 0; j < 4; j++) s += hs[r][lane + 64*j];
    s = wave_sum64(s);
    float m = s * (1.0f/256.0f);
    float v = 0.f;
    #pragma unroll
    for (int j = 0; j < 4; j++){ float d = hs[r][lane+64*j] - m; v += d*d; }
    v = wave_sum64(v) * (1.0f/256.0f);
    float inv = 1.0f / sqrtf(v + EPSv);
    #pragma unroll
    for (int j = 0; j < 4; j++){
      int c = lane + 64*j;
      float y = (hs[r][c]-m)*inv*g[c] + beta[c];
      out[(size_t)(r0+r)*256 + c] = fmaxf(y, 0.f);
    }
  }
}

// ---------------- kernel 2: features = relu(LN(h @ W2 + b2)) : 8192x256 -> 8192x512
__global__ __launch_bounds__(256) void k_rp2(const float* __restrict__ X,
    const float* __restrict__ W, const float* __restrict__ bias,
    const float* __restrict__ g, const float* __restrict__ beta,
    float* __restrict__ out)
{
  __shared__ float xs[8][256];
  __shared__ float fs[8][512];
  const int tid = threadIdx.x;
  const int r0  = blockIdx.x * 8;
  for (int i = tid; i < 8*64; i += 256){
    int r = i >> 6, c = i & 63;
    ((float4*)xs[r])[c] = ((const float4*)X)[(size_t)(r0+r)*64 + c];
  }
  __syncthreads();
  const int c0 = tid, c1 = tid + 256;
  float a0[8], a1[8];
  #pragma unroll
  for (int r = 0; r < 8; r++){ a0[r] = bias[c0]; a1[r] = bias[c1]; }
  for (int k = 0; k < 256; k += 4){
    float w00=W[(k+0)*512+c0], w10=W[(k+1)*512+c0], w20=W[(k+2)*512+c0], w30=W[(k+3)*512+c0];
    float w01=W[(k+0)*512+c1], w11=W[(k+1)*512+c1], w21=W[(k+2)*512+c1], w31=W[(k+3)*512+c1];
    #pragma unroll
    for (int r = 0; r < 8; r++){
      float4 x4 = *(const float4*)&xs[r][k];
      a0[r] += x4.x*w00 + x4.y*w10 + x4.z*w20 + x4.w*w30;
      a1[r] += x4.x*w01 + x4.y*w11 + x4.z*w21 + x4.w*w31;
    }
  }
  #pragma unroll
  for (int r = 0; r < 8; r++){ fs[r][c0] = a0[r]; fs[r][c1] = a1[r]; }
  __syncthreads();
  const int wave = tid >> 6, lane = tid & 63;
  #pragma unroll
  for (int rr = 0; rr < 2; rr++){
    int r = wave*2 + rr;
    float s = 0.f;
    #pragma unroll
    for (int j = 0; j < 8; j++) s += fs[r][lane + 64*j];
    s = wave_sum64(s);
    float m = s * (1.0f/512.0f);
    float v = 0.f;
    #pragma unroll
    for (int j = 0; j < 8; j++){ float d = fs[r][lane+64*j] - m; v += d*d; }
    v = wave_sum64(v) * (1.0f/512.0f);
    float inv = 1.0f / sqrtf(v + EPSv);
    #pragma unroll
    for (int j = 0; j < 8; j++){
      int c = lane + 64*j;
      float y = (fs[r][c]-m)*inv*g[c] + beta[c];
      out[(size_t)(r0+r)*512 + c] = fmaxf(y, 0.f);
    }
  }
}

// ---------------- kernel 3: logits -> softmax -> top3 + per-expert lists
__global__ __launch_bounds__(256) void k_gate(const float* __restrict__ F,
    const float* __restrict__ W, const float* __restrict__ bop,
    float* __restrict__ dout, int* __restrict__ cnt, int* __restrict__ list)
{
  __shared__ float fs[8][512];
  __shared__ float part[4][8][64];
  __shared__ float lg[8][64];
  const int tid = threadIdx.x;
  const int r0  = blockIdx.x * 8;
  for (int i = tid; i < 8*128; i += 256){
    int r = i >> 7, c = i & 127;
    ((float4*)fs[r])[c] = ((const float4*)F)[(size_t)(r0+r)*128 + c];
  }
  __syncthreads();
  const int col = tid & 63, seg = tid >> 6;
  float acc[8] = {0,0,0,0,0,0,0,0};
  const int kbase = seg * 128;
  for (int k = kbase; k < kbase + 128; k++){
    float w = W[k*64 + col];
    #pragma unroll
    for (int r = 0; r < 8; r++) acc[r] += fs[r][k] * w;
  }
  #pragma unroll
  for (int r = 0; r < 8; r++) part[seg][r][col] = acc[r];
  __syncthreads();
  for (int i = tid; i < 8*64; i += 256){
    int r = i >> 6, c = i & 63;
    lg[r][c] = part[0][r][c] + part[1][r][c] + part[2][r][c] + part[3][r][c] + bop[c];
  }
  __syncthreads();
  const int wave = tid >> 6, lane = tid & 63;
  for (int rr = 0; rr < 2; rr++){
    int r = wave*2 + rr, row = r0 + r;
    float l = lg[r][lane];
    float mx = l;
    #pragma unroll
    for (int o = 32; o; o >>= 1) mx = fmaxf(mx, __shfl_xor(mx, o, 64));
    float p = expf(l - mx);
    float s = wave_sum64(p);
    p /= s;
    float pv = p;
    for (int j = 0; j < 3; j++){
      float v = pv; int idx = lane;
      #pragma unroll
      for (int o = 32; o; o >>= 1){
        float ov = __shfl_xor(v, o, 64);
        int   oi = __shfl_xor(idx, o, 64);
        if (ov > v || (ov == v && oi < idx)){ v = ov; idx = oi; }
      }
      if (lane == 0){
        dout[(size_t)row*3 + j]                 = v;           // top_probs
        dout[(size_t)Bv*3 + (size_t)row*3 + j]  = (float)idx;  // top_idx (as float)
      }
      if (v >= CONFv){
        if (lane == 0){
          int pos = atomicAdd(&cnt[idx], 1);
          list[idx*Bv + pos] = (row << 2) | j;
        }
      } else {
        if (lane < 16) dout[(size_t)Bv*6 + (size_t)row*48 + j*16 + lane] = 0.f;
      }
      if (lane == idx) pv = -1.0f;
    }
  }
}

// ---------------- kernel 3.5: build compacted (expert, tile) work list ----
__global__ void k_sched(const int* __restrict__ cnt, int* __restrict__ work,
                        int* __restrict__ ntl)
{
  __shared__ int base[64];
  if (threadIdx.x == 0){
    int s = 0;
    for (int e = 0; e < 64; e++){ base[e] = s; s += (cnt[e] + 15) >> 4; }
    *ntl = s;
  }
  __syncthreads();
  int e  = threadIdx.x;             // 64 threads
  int nt = (cnt[e] + 15) >> 4;
  int b0 = base[e];
  for (int t = 0; t < nt; t++) work[b0 + t] = (e << 16) | t;
}

// ---------------- kernel 4: expert MLP on selected (row,k) pairs ----------
__global__ __launch_bounds__(256) void k_expert(const float* __restrict__ F,
    const float* __restrict__ W1, const float* __restrict__ b1,
    const float* __restrict__ g,  const float* __restrict__ beta,
    const float* __restrict__ W2, const float* __restrict__ b2,
    const int* __restrict__ cnt,  const int* __restrict__ list,
    const int* __restrict__ work, const int* __restrict__ ntiles,
    float* __restrict__ dout)
{
  if ((int)blockIdx.x >= *ntiles) return;
  const int desc = work[blockIdx.x];
  const int e = desc >> 16, t = desc & 0xffff;
  const int n = cnt[e];
  const int base = t * 16;
  const int m = min(16, n - base);
  __shared__ float fs[16][512];
  __shared__ float zs[16][257];    // pad to break phase-2 bank conflicts
  __shared__ int ent[16];
  const int tid = threadIdx.x;
  if (tid < 16) ent[tid] = list[e*Bv + base + ((tid < m) ? tid : 0)];
  __syncthreads();
  for (int i = tid; i < 16*128; i += 256){
    int r = i >> 7, c = i & 127;
    int row = ent[r] >> 2;
    ((float4*)fs[r])[c] = ((const float4*)F)[(size_t)row*128 + c];
  }
  const float* W1e = W1 + (size_t)e * 512 * 256;
  __syncthreads();
  const int col = tid;
  float acc[16];
  #pragma unroll
  for (int r = 0; r < 16; r++) acc[r] = 0.f;
  for (int k = 0; k < 512; k += 4){
    float w0 = W1e[(k+0)*256+col], w1 = W1e[(k+1)*256+col];
    float w2 = W1e[(k+2)*256+col], w3 = W1e[(k+3)*256+col];
    #pragma unroll
    for (int r = 0; r < 16; r++){
      float4 x4 = *(const float4*)&fs[r][k];
      acc[r] += x4.x*w0 + x4.y*w1 + x4.z*w2 + x4.w*w3;
    }
  }
  const float bb = b1[e*256 + col];
  #pragma unroll
  for (int r = 0; r < 16; r++) zs[r][col] = acc[r] + bb;
  __syncthreads();
  const int wave = tid >> 6, lane = tid & 63;
  #pragma unroll
  for (int rr = 0; rr < 4; rr++){
    int r = wave*4 + rr;
    float s = 0.f;
    #pragma unroll
    for (int j = 0; j < 4; j++) s += zs[r][lane + 64*j];
    s = wave_sum64(s);
    float mm = s * (1.0f/256.0f);
    float v = 0.f;
    #pragma unroll
    for (int j = 0; j < 4; j++){ float d = zs[r][lane+64*j] - mm; v += d*d; }
    v = wave_sum64(v) * (1.0f/256.0f);
    float inv = 1.0f / sqrtf(v + EPSv);
    #pragma unroll
    for (int j = 0; j < 4; j++){
      int c = lane + 64*j;
      float y = (zs[r][c]-mm)*inv*g[e*256+c] + beta[e*256+c];
      zs[r][c] = fmaxf(y, 0.f);
    }
  }
  __syncthreads();
  const float* W2e = W2 + (size_t)e * 256 * 16;
  const int r = tid >> 4, p = tid & 15;
  float o = b2[e*16 + p];
  for (int c = 0; c < 256; c++) o += zs[r][c] * W2e[c*16 + p];
  if (r < m){
    int ev = ent[r]; int row = ev >> 2, j = ev & 3;
    dout[(size_t)Bv*6 + (size_t)row*48 + j*16 + p] = o;
  }
}

extern "C" void kernel_launch(void* const* d_in, const int* in_sizes, int n_in,
                              void* d_out, int out_size, void* d_ws, size_t ws_size,
                              hipStream_t stream)
{
  const float* X   = (const float*)d_in[0];
  const float* w1  = (const float*)d_in[1];
  const float* b1  = (const float*)d_in[2];
  const float* g1  = (const float*)d_in[3];
  const float* be1 = (const float*)d_in[4];
  const float* w2  = (const float*)d_in[5];
  const float* b2  = (const float*)d_in[6];
  const float* g2  = (const float*)d_in[7];
  const float* be2 = (const float*)d_in[8];
  const float* opw = (const float*)d_in[9];
  const float* opb = (const float*)d_in[10];
  const float* pw1 = (const float*)d_in[11];
  const float* pb1 = (const float*)d_in[12];
  const float* pg  = (const float*)d_in[13];
  const float* pbe = (const float*)d_in[14];
  const float* pw2 = (const float*)d_in[15];
  const float* pb2 = (const float*)d_in[16];
  float* out = (float*)d_out;
  char*  ws  = (char*)d_ws;

  float* h    = (float*)(ws);                              // 8 MB
  float* feat = (float*)(ws + (size_t)8*1024*1024);        // 16 MB
  int*   cnt  = (int*)  (ws + (size_t)24*1024*1024);       // 64 ints
  int*   ntl  = cnt + 64;                                  // 1 int
  int*   work = cnt + 128;                                 // <=1600 ints
  int*   list = cnt + 4096;                                // 64*8192 ints (2 MB)

  k_zero  <<<1,    64, 0, stream>>>(cnt);
  k_rp1   <<<1024, 256, 0, stream>>>(X, w1, b1, g1, be1, h);
  k_rp2   <<<1024, 256, 0, stream>>>(h, w2, b2, g2, be2, feat);
  k_gate  <<<1024, 256, 0, stream>>>(feat, opw, opb, out, cnt, list);
  k_sched <<<1,    64, 0, stream>>>(cnt, work, ntl);
  k_expert<<<1600, 256, 0, stream>>>(feat, pw1, pb1, pg, pbe, pw2, pb2,
                                     cnt, list, work, ntl, out);
}

// Round 2
// 231.996 us; speedup vs baseline: 1.1371x; 1.1371x over previous
//
#include <hip/hip_runtime.h>
#include <math.h>

#define Bv   8192
#define EPSv 1e-5f
#define CONFv 0.1f

typedef __attribute__((ext_vector_type(8))) short short8;
typedef __attribute__((ext_vector_type(4))) float f32x4;

__device__ __forceinline__ float wave_sum64(float v){
  #pragma unroll
  for (int o = 32; o; o >>= 1) v += __shfl_xor(v, o, 64);
  return v;
}

// ---------------- kernel 0: zero the per-expert counters ----------------
__global__ void k_zero(int* __restrict__ cnt){
  if (threadIdx.x < 64) cnt[threadIdx.x] = 0;
}

// ---------------- kernel 1: h = relu(LN(X @ W1 + b1)) : 8192x128 -> 8192x256
__global__ __launch_bounds__(256) void k_rp1(const float* __restrict__ X,
    const float* __restrict__ W, const float* __restrict__ bias,
    const float* __restrict__ g, const float* __restrict__ beta,
    float* __restrict__ out)
{
  __shared__ float xs[8][128];
  __shared__ float hs[8][256];
  const int tid = threadIdx.x;
  const int r0  = blockIdx.x * 8;
  for (int i = tid; i < 8*32; i += 256){
    int r = i >> 5, c = i & 31;
    ((float4*)xs[r])[c] = ((const float4*)X)[(size_t)(r0 + r)*32 + c];
  }
  __syncthreads();
  const int col = tid;
  float acc[8];
  #pragma unroll
  for (int r = 0; r < 8; r++) acc[r] = bias[col];
  for (int k = 0; k < 128; k += 4){
    float w0 = W[(k+0)*256+col], w1 = W[(k+1)*256+col];
    float w2 = W[(k+2)*256+col], w3 = W[(k+3)*256+col];
    #pragma unroll
    for (int r = 0; r < 8; r++){
      float4 x4 = *(const float4*)&xs[r][k];
      acc[r] += x4.x*w0 + x4.y*w1 + x4.z*w2 + x4.w*w3;
    }
  }
  #pragma unroll
  for (int r = 0; r < 8; r++) hs[r][col] = acc[r];
  __syncthreads();
  const int wave = tid >> 6, lane = tid & 63;
  #pragma unroll
  for (int rr = 0; rr < 2; rr++){
    int r = wave*2 + rr;
    float s = 0.f;
    #pragma unroll
    for (int j = 0; j < 4; j++) s += hs[r][lane + 64*j];
    s = wave_sum64(s);
    float m = s * (1.0f/256.0f);
    float v = 0.f;
    #pragma unroll
    for (int j = 0; j < 4; j++){ float d = hs[r][lane+64*j] - m; v += d*d; }
    v = wave_sum64(v) * (1.0f/256.0f);
    float inv = 1.0f / sqrtf(v + EPSv);
    #pragma unroll
    for (int j = 0; j < 4; j++){
      int c = lane + 64*j;
      float y = (hs[r][c]-m)*inv*g[c] + beta[c];
      out[(size_t)(r0+r)*256 + c] = fmaxf(y, 0.f);
    }
  }
}

// ---------------- kernel 2: features = relu(LN(h @ W2 + b2)) : 8192x256 -> 8192x512
__global__ __launch_bounds__(256) void k_rp2(const float* __restrict__ X,
    const float* __restrict__ W, const float* __restrict__ bias,
    const float* __restrict__ g, const float* __restrict__ beta,
    float* __restrict__ out)
{
  __shared__ float xs[8][256];
  __shared__ float fs[8][512];
  const int tid = threadIdx.x;
  const int r0  = blockIdx.x * 8;
  for (int i = tid; i < 8*64; i += 256){
    int r = i >> 6, c = i & 63;
    ((float4*)xs[r])[c] = ((const float4*)X)[(size_t)(r0+r)*64 + c];
  }
  __syncthreads();
  const int c0 = tid, c1 = tid + 256;
  float a0[8], a1[8];
  #pragma unroll
  for (int r = 0; r < 8; r++){ a0[r] = bias[c0]; a1[r] = bias[c1]; }
  for (int k = 0; k < 256; k += 4){
    float w00=W[(k+0)*512+c0], w10=W[(k+1)*512+c0], w20=W[(k+2)*512+c0], w30=W[(k+3)*512+c0];
    float w01=W[(k+0)*512+c1], w11=W[(k+1)*512+c1], w21=W[(k+2)*512+c1], w31=W[(k+3)*512+c1];
    #pragma unroll
    for (int r = 0; r < 8; r++){
      float4 x4 = *(const float4*)&xs[r][k];
      a0[r] += x4.x*w00 + x4.y*w10 + x4.z*w20 + x4.w*w30;
      a1[r] += x4.x*w01 + x4.y*w11 + x4.z*w21 + x4.w*w31;
    }
  }
  #pragma unroll
  for (int r = 0; r < 8; r++){ fs[r][c0] = a0[r]; fs[r][c1] = a1[r]; }
  __syncthreads();
  const int wave = tid >> 6, lane = tid & 63;
  #pragma unroll
  for (int rr = 0; rr < 2; rr++){
    int r = wave*2 + rr;
    float s = 0.f;
    #pragma unroll
    for (int j = 0; j < 8; j++) s += fs[r][lane + 64*j];
    s = wave_sum64(s);
    float m = s * (1.0f/512.0f);
    float v = 0.f;
    #pragma unroll
    for (int j = 0; j < 8; j++){ float d = fs[r][lane+64*j] - m; v += d*d; }
    v = wave_sum64(v) * (1.0f/512.0f);
    float inv = 1.0f / sqrtf(v + EPSv);
    #pragma unroll
    for (int j = 0; j < 8; j++){
      int c = lane + 64*j;
      float y = (fs[r][c]-m)*inv*g[c] + beta[c];
      out[(size_t)(r0+r)*512 + c] = fmaxf(y, 0.f);
    }
  }
}

// ---------------- kernel 3: logits -> softmax -> top3 + per-expert lists
__global__ __launch_bounds__(256) void k_gate(const float* __restrict__ F,
    const float* __restrict__ W, const float* __restrict__ bop,
    float* __restrict__ dout, int* __restrict__ cnt, int* __restrict__ list)
{
  __shared__ float fs[8][512];
  __shared__ float part[4][8][64];
  __shared__ float lg[8][64];
  const int tid = threadIdx.x;
  const int r0  = blockIdx.x * 8;
  for (int i = tid; i < 8*128; i += 256){
    int r = i >> 7, c = i & 127;
    ((float4*)fs[r])[c] = ((const float4*)F)[(size_t)(r0+r)*128 + c];
  }
  __syncthreads();
  const int col = tid & 63, seg = tid >> 6;
  float acc[8] = {0,0,0,0,0,0,0,0};
  const int kbase = seg * 128;
  for (int k = kbase; k < kbase + 128; k++){
    float w = W[k*64 + col];
    #pragma unroll
    for (int r = 0; r < 8; r++) acc[r] += fs[r][k] * w;
  }
  #pragma unroll
  for (int r = 0; r < 8; r++) part[seg][r][col] = acc[r];
  __syncthreads();
  for (int i = tid; i < 8*64; i += 256){
    int r = i >> 6, c = i & 63;
    lg[r][c] = part[0][r][c] + part[1][r][c] + part[2][r][c] + part[3][r][c] + bop[c];
  }
  __syncthreads();
  const int wave = tid >> 6, lane = tid & 63;
  for (int rr = 0; rr < 2; rr++){
    int r = wave*2 + rr, row = r0 + r;
    float l = lg[r][lane];
    float mx = l;
    #pragma unroll
    for (int o = 32; o; o >>= 1) mx = fmaxf(mx, __shfl_xor(mx, o, 64));
    float p = expf(l - mx);
    float s = wave_sum64(p);
    p /= s;
    float pv = p;
    for (int j = 0; j < 3; j++){
      float v = pv; int idx = lane;
      #pragma unroll
      for (int o = 32; o; o >>= 1){
        float ov = __shfl_xor(v, o, 64);
        int   oi = __shfl_xor(idx, o, 64);
        if (ov > v || (ov == v && oi < idx)){ v = ov; idx = oi; }
      }
      if (lane == 0){
        dout[(size_t)row*3 + j]                 = v;
        dout[(size_t)Bv*3 + (size_t)row*3 + j]  = (float)idx;
      }
      if (v >= CONFv){
        if (lane == 0){
          int pos = atomicAdd(&cnt[idx], 1);
          list[idx*Bv + pos] = (row << 2) | j;
        }
      } else {
        if (lane < 16) dout[(size_t)Bv*6 + (size_t)row*48 + j*16 + lane] = 0.f;
      }
      if (lane == idx) pv = -1.0f;
    }
  }
}

// ---------------- kernel 3.5: build compacted (expert, tile32) work list ----
__global__ void k_sched(const int* __restrict__ cnt, int* __restrict__ work,
                        int* __restrict__ ntl)
{
  __shared__ int base[64];
  if (threadIdx.x == 0){
    int s = 0;
    for (int e = 0; e < 64; e++){ base[e] = s; s += (cnt[e] + 31) >> 5; }
    *ntl = s;
  }
  __syncthreads();
  int e  = threadIdx.x;
  int nt = (cnt[e] + 31) >> 5;
  int b0 = base[e];
  for (int t = 0; t < nt; t++) work[b0 + t] = (e << 16) | t;
}

// ---------------- kernel 4: expert MLP, split-bf16 3-pass MFMA GEMM1 -------
// Tile: 32 rows x 256 cols, K=512. Block = 4 waves; wave handles 64 cols.
// A (features) staged in LDS as hi/lo bf16 planes, XOR-swizzled 16B groups.
// W converted fp32->hi/lo bf16 in-register per fragment (trunc split).
// Error per product ~2^-16 rel -> params error ~1e-5, safe vs threshold.
__global__ __launch_bounds__(256) void k_expert(const float* __restrict__ F,
    const float* __restrict__ W1, const float* __restrict__ b1,
    const float* __restrict__ g,  const float* __restrict__ beta,
    const float* __restrict__ W2, const float* __restrict__ b2,
    const int* __restrict__ cnt,  const int* __restrict__ list,
    const int* __restrict__ work, const int* __restrict__ ntiles,
    float* __restrict__ dout)
{
  extern __shared__ unsigned char smem[];          // 65536 B dynamic
  unsigned short* xh = (unsigned short*)smem;      // [32][512] bf16-hi (swizzled)
  unsigned short* xl = xh + 32*512;                // [32][512] bf16-lo
  float* zs = (float*)smem;                        // [32][265] overlay after GEMM1

  if ((int)blockIdx.x >= *ntiles) return;
  const int desc = work[blockIdx.x];
  const int e = desc >> 16, t = desc & 0xffff;
  const int n = cnt[e];
  const int base = t * 32;
  const int m = min(32, n - base);
  const int* lrow = list + e*Bv + base;
  const int tid = threadIdx.x;

  // ---- stage features -> hi/lo bf16 planes (swizzled groups of 8 ushorts)
  for (int i = tid; i < 32*128; i += 256){
    int r = i >> 7, c4 = i & 127;                  // c4: float4 index within row
    int ev = lrow[(r < m) ? r : 0];
    int row = ev >> 2;
    float4 v = ((const float4*)(F + (size_t)row*512))[c4];
    unsigned u0 = __float_as_uint(v.x), u1 = __float_as_uint(v.y);
    unsigned u2 = __float_as_uint(v.z), u3 = __float_as_uint(v.w);
    float l0f = v.x - __uint_as_float(u0 & 0xffff0000u);
    float l1f = v.y - __uint_as_float(u1 & 0xffff0000u);
    float l2f = v.z - __uint_as_float(u2 & 0xffff0000u);
    float l3f = v.w - __uint_as_float(u3 & 0xffff0000u);
    unsigned hpack0 = (u0 >> 16) | (u1 & 0xffff0000u);
    unsigned hpack1 = (u2 >> 16) | (u3 & 0xffff0000u);
    unsigned lpack0 = (__float_as_uint(l0f) >> 16) | (__float_as_uint(l1f) & 0xffff0000u);
    unsigned lpack1 = (__float_as_uint(l2f) >> 16) | (__float_as_uint(l3f) & 0xffff0000u);
    int gidx = c4 >> 1, half = c4 & 1;
    int off = r*512 + ((gidx ^ (r & 7)) << 3) + half*4;   // ushort units, 8B aligned
    ((unsigned*)(xh + off))[0] = hpack0;
    ((unsigned*)(xh + off))[1] = hpack1;
    ((unsigned*)(xl + off))[0] = lpack0;
    ((unsigned*)(xl + off))[1] = lpack1;
  }
  __syncthreads();

  const int wave = tid >> 6, lane = tid & 63;
  const int lquad = lane >> 4, l15 = lane & 15;
  const float* W1e = W1 + (size_t)e * 512 * 256;
  const int colbase = wave * 64;

  f32x4 acc[2][4];
  #pragma unroll
  for (int mt = 0; mt < 2; mt++)
    #pragma unroll
    for (int nt = 0; nt < 4; nt++)
      acc[mt][nt] = (f32x4){0.f, 0.f, 0.f, 0.f};

  for (int ks = 0; ks < 512; ks += 32){
    short8 ah[2], al[2];
    int gk = (ks >> 3) + lquad;
    #pragma unroll
    for (int mt = 0; mt < 2; mt++){
      int r = mt*16 + l15;
      int off = r*512 + ((gk ^ (r & 7)) << 3);
      ah[mt] = *(const short8*)(xh + off);
      al[mt] = *(const short8*)(xl + off);
    }
    #pragma unroll
    for (int nt = 0; nt < 4; nt++){
      int col = colbase + nt*16 + l15;
      const float* wp = W1e + (size_t)(ks + lquad*8)*256 + col;
      short8 bh, bl;
      #pragma unroll
      for (int j = 0; j < 8; j++){
        float w = wp[(size_t)j*256];
        unsigned u = __float_as_uint(w);
        float lo = w - __uint_as_float(u & 0xffff0000u);
        bh[j] = (short)(u >> 16);
        bl[j] = (short)(__float_as_uint(lo) >> 16);
      }
      #pragma unroll
      for (int mt = 0; mt < 2; mt++){
        acc[mt][nt] = __builtin_amdgcn_mfma_f32_16x16x32_bf16(al[mt], bh, acc[mt][nt], 0, 0, 0);
        acc[mt][nt] = __builtin_amdgcn_mfma_f32_16x16x32_bf16(ah[mt], bl, acc[mt][nt], 0, 0, 0);
        acc[mt][nt] = __builtin_amdgcn_mfma_f32_16x16x32_bf16(ah[mt], bh, acc[mt][nt], 0, 0, 0);
      }
    }
  }
  __syncthreads();   // all waves done reading x-planes; zs overlays them now

  // ---- z = acc + b1  (C/D layout: col = lane&15, row = quad*4 + reg)
  #pragma unroll
  for (int nt = 0; nt < 4; nt++){
    int col = colbase + nt*16 + l15;
    float bb = b1[e*256 + col];
    #pragma unroll
    for (int mt = 0; mt < 2; mt++)
      #pragma unroll
      for (int rg = 0; rg < 4; rg++){
        int rl = mt*16 + lquad*4 + rg;
        zs[rl*265 + col] = acc[mt][nt][rg] + bb;
      }
  }
  __syncthreads();

  // ---- LN + ReLU (wave handles 8 rows)
  {
    float gv[4], bv[4];
    #pragma unroll
    for (int j = 0; j < 4; j++){
      gv[j] = g[e*256 + lane + 64*j];
      bv[j] = beta[e*256 + lane + 64*j];
    }
    for (int rr = 0; rr < 8; rr++){
      int r = wave*8 + rr;
      float x[4];
      float s = 0.f;
      #pragma unroll
      for (int j = 0; j < 4; j++){ x[j] = zs[r*265 + lane + 64*j]; s += x[j]; }
      s = wave_sum64(s);
      float mm = s * (1.0f/256.0f);
      float v = 0.f;
      #pragma unroll
      for (int j = 0; j < 4; j++){ float d = x[j] - mm; v += d*d; }
      v = wave_sum64(v) * (1.0f/256.0f);
      float inv = 1.0f / sqrtf(v + EPSv);
      #pragma unroll
      for (int j = 0; j < 4; j++){
        float y = (x[j] - mm)*inv*gv[j] + bv[j];
        zs[r*265 + lane + 64*j] = fmaxf(y, 0.f);
      }
    }
  }
  __syncthreads();

  // ---- GEMM2: out[r][p] = b2 + zs[r][:] . W2e[:,p]   (fp32, tiny)
  const float* W2e = W2 + (size_t)e * 256 * 16;
  const int r = tid >> 3, pp = (tid & 7) * 2;
  float o0 = b2[e*16 + pp], o1 = b2[e*16 + pp + 1];
  #pragma unroll 8
  for (int c = 0; c < 256; c++){
    float z = zs[r*265 + c];
    float2 w = *(const float2*)(W2e + (size_t)c*16 + pp);
    o0 += z * w.x;
    o1 += z * w.y;
  }
  if (r < m){
    int ev = lrow[r];
    int row = ev >> 2, j = ev & 3;
    float* dst = dout + (size_t)Bv*6 + (size_t)row*48 + j*16 + pp;
    dst[0] = o0;
    dst[1] = o1;
  }
}

extern "C" void kernel_launch(void* const* d_in, const int* in_sizes, int n_in,
                              void* d_out, int out_size, void* d_ws, size_t ws_size,
                              hipStream_t stream)
{
  const float* X   = (const float*)d_in[0];
  const float* w1  = (const float*)d_in[1];
  const float* b1  = (const float*)d_in[2];
  const float* g1  = (const float*)d_in[3];
  const float* be1 = (const float*)d_in[4];
  const float* w2  = (const float*)d_in[5];
  const float* b2  = (const float*)d_in[6];
  const float* g2  = (const float*)d_in[7];
  const float* be2 = (const float*)d_in[8];
  const float* opw = (const float*)d_in[9];
  const float* opb = (const float*)d_in[10];
  const float* pw1 = (const float*)d_in[11];
  const float* pb1 = (const float*)d_in[12];
  const float* pg  = (const float*)d_in[13];
  const float* pbe = (const float*)d_in[14];
  const float* pw2 = (const float*)d_in[15];
  const float* pb2 = (const float*)d_in[16];
  float* out = (float*)d_out;
  char*  ws  = (char*)d_ws;

  float* h    = (float*)(ws);                              // 8 MB
  float* feat = (float*)(ws + (size_t)8*1024*1024);        // 16 MB
  int*   cnt  = (int*)  (ws + (size_t)24*1024*1024);       // 64 ints
  int*   ntl  = cnt + 64;                                  // 1 int
  int*   work = cnt + 128;                                 // <=832 ints
  int*   list = cnt + 4096;                                // 64*8192 ints (2 MB)

  k_zero  <<<1,    64, 0, stream>>>(cnt);
  k_rp1   <<<1024, 256, 0, stream>>>(X, w1, b1, g1, be1, h);
  k_rp2   <<<1024, 256, 0, stream>>>(h, w2, b2, g2, be2, feat);
  k_gate  <<<1024, 256, 0, stream>>>(feat, opw, opb, out, cnt, list);
  k_sched <<<1,    64, 0, stream>>>(cnt, work, ntl);
  k_expert<<<832,  256, 65536, stream>>>(feat, pw1, pb1, pg, pbe, pw2, pb2,
                                         cnt, list, work, ntl, out);
}

// Round 3
// 221.060 us; speedup vs baseline: 1.1933x; 1.0495x over previous
//
#include <hip/hip_runtime.h>
#include <math.h>

#define Bv   8192
#define EPSv 1e-5f
#define CONFv 0.1f
#define MB (1024*1024)

typedef __attribute__((ext_vector_type(8))) short short8;
typedef __attribute__((ext_vector_type(4))) float f32x4;

__device__ __forceinline__ float wave_sum64(float v){
  #pragma unroll
  for (int o = 32; o; o >>= 1) v += __shfl_xor(v, o, 64);
  return v;
}

// Truncated 3-way split: x = hi + mid + lo + r, |r| <= 2^-24 |x|, all exact subs.
__device__ __forceinline__ void split3f(float x, short &h, short &m, short &l){
  unsigned u = __float_as_uint(x);
  h = (short)(u >> 16);
  float r1 = x - __uint_as_float(u & 0xffff0000u);
  unsigned u1 = __float_as_uint(r1);
  m = (short)(u1 >> 16);
  float r2 = r1 - __uint_as_float(u1 & 0xffff0000u);
  l = (short)(__float_as_uint(r2) >> 16);
}

// 6-pass accumulate, small terms first.
__device__ __forceinline__ f32x4 mfma6(short8 ah, short8 am, short8 al,
                                       short8 bh, short8 bm, short8 bl, f32x4 c){
  c = __builtin_amdgcn_mfma_f32_16x16x32_bf16(al, bh, c, 0, 0, 0);
  c = __builtin_amdgcn_mfma_f32_16x16x32_bf16(ah, bl, c, 0, 0, 0);
  c = __builtin_amdgcn_mfma_f32_16x16x32_bf16(am, bm, c, 0, 0, 0);
  c = __builtin_amdgcn_mfma_f32_16x16x32_bf16(am, bh, c, 0, 0, 0);
  c = __builtin_amdgcn_mfma_f32_16x16x32_bf16(ah, bm, c, 0, 0, 0);
  c = __builtin_amdgcn_mfma_f32_16x16x32_bf16(ah, bh, c, 0, 0, 0);
  return c;
}

// ---------------- kernel 0: zero the per-expert counters ----------------
__global__ void k_zero(int* __restrict__ cnt){
  if (threadIdx.x < 64) cnt[threadIdx.x] = 0;
}

// ---------------- pack W (K x N fp32, row-major) -> 3 bf16 planes in MFMA
// B-fragment order: idx = ((ntile*ktiles + ktile)*64 + lane)*8 + j,
// lane = ((k>>3)&3)*16 + (n&15), j = k&7.
__global__ __launch_bounds__(256) void k_packW(const float* __restrict__ W,
    unsigned short* __restrict__ dst, int total, int nlog2, int ktiles)
{
  int gid = blockIdx.x*256 + threadIdx.x;
  if (gid >= total) return;
  int k = gid >> nlog2, n = gid & ((1 << nlog2) - 1);
  short h, m, l;
  split3f(W[gid], h, m, l);
  int idx = (((n >> 4)*ktiles + (k >> 5))*64 + (((k >> 3) & 3)*16 + (n & 15)))*8 + (k & 7);
  dst[idx]           = (unsigned short)h;
  dst[total + idx]   = (unsigned short)m;
  dst[2*total + idx] = (unsigned short)l;
}

// ---------------- kernel 1: h = relu(LN(X @ W1 + b1)), MFMA 6-pass --------
// Tile 32 rows x 256 cols, K=128. 4 waves x 64 cols. Emits h as 3 bf16 planes.
__global__ __launch_bounds__(256) void k_rp1_mfma(const float* __restrict__ X,
    const unsigned short* __restrict__ w1p, const float* __restrict__ bias,
    const float* __restrict__ g, const float* __restrict__ beta,
    unsigned short* __restrict__ hp)
{
  __shared__ float xs[32*128];
  __shared__ float part[4][32][2];
  const int tid = threadIdx.x;
  const int r0  = blockIdx.x * 32;
  for (int i = tid; i < 32*32; i += 256){
    int r = i >> 5, c4 = i & 31;
    float4 v = ((const float4*)X)[(size_t)(r0+r)*32 + c4];
    int off = r*128 + (((c4 >> 1) ^ (r & 7)) << 3) + ((c4 & 1) << 2);
    *(float4*)(xs + off) = v;
  }
  __syncthreads();
  const int wave = tid >> 6, lane = tid & 63, lquad = lane >> 4, l15 = lane & 15;
  f32x4 acc[2][4];
  #pragma unroll
  for (int mt = 0; mt < 2; mt++)
    #pragma unroll
    for (int nt = 0; nt < 4; nt++) acc[mt][nt] = (f32x4){0.f,0.f,0.f,0.f};

  const int pstride = 128*256;
  for (int ks4 = 0; ks4 < 4; ks4++){
    short8 ah[2], am[2], al[2];
    #pragma unroll
    for (int mt = 0; mt < 2; mt++){
      int r = mt*16 + l15;
      const float* ap = xs + r*128 + (((ks4*4 + lquad) ^ (r & 7)) << 3);
      float4 a0 = *(const float4*)ap;
      float4 a1 = *(const float4*)(ap + 4);
      float av[8] = {a0.x,a0.y,a0.z,a0.w,a1.x,a1.y,a1.z,a1.w};
      #pragma unroll
      for (int j = 0; j < 8; j++){
        short hh, mm2, ll;
        split3f(av[j], hh, mm2, ll);
        ah[mt][j] = hh; am[mt][j] = mm2; al[mt][j] = ll;
      }
    }
    #pragma unroll
    for (int nt = 0; nt < 4; nt++){
      int ntg = wave*4 + nt;
      const unsigned short* bp = w1p + (size_t)(((ntg*4 + ks4)*64 + lane)*8);
      short8 bh = *(const short8*)bp;
      short8 bm = *(const short8*)(bp + pstride);
      short8 bl = *(const short8*)(bp + 2*pstride);
      #pragma unroll
      for (int mt = 0; mt < 2; mt++)
        acc[mt][nt] = mfma6(ah[mt], am[mt], al[mt], bh, bm, bl, acc[mt][nt]);
    }
  }

  float bcol[4], gcol[4], becol[4];
  #pragma unroll
  for (int nt = 0; nt < 4; nt++){
    int col = (wave*4 + nt)*16 + l15;
    bcol[nt] = bias[col]; gcol[nt] = g[col]; becol[nt] = beta[col];
  }
  #pragma unroll
  for (int mt = 0; mt < 2; mt++)
    #pragma unroll
    for (int reg = 0; reg < 4; reg++){
      float s = 0.f, q = 0.f;
      #pragma unroll
      for (int nt = 0; nt < 4; nt++){
        float z = acc[mt][nt][reg] + bcol[nt];
        s += z; q += z*z;
      }
      #pragma unroll
      for (int o = 1; o < 16; o <<= 1){ s += __shfl_xor(s, o, 64); q += __shfl_xor(q, o, 64); }
      int row = mt*16 + lquad*4 + reg;
      if (l15 == 0){ part[wave][row][0] = s; part[wave][row][1] = q; }
    }
  __syncthreads();
  #pragma unroll
  for (int mt = 0; mt < 2; mt++)
    #pragma unroll
    for (int reg = 0; reg < 4; reg++){
      int row = mt*16 + lquad*4 + reg;
      float s = part[0][row][0] + part[1][row][0] + part[2][row][0] + part[3][row][0];
      float q = part[0][row][1] + part[1][row][1] + part[2][row][1] + part[3][row][1];
      float mean = s * (1.0f/256.0f);
      float var  = q * (1.0f/256.0f) - mean*mean;
      float inv  = 1.0f / sqrtf(var + EPSv);
      #pragma unroll
      for (int nt = 0; nt < 4; nt++){
        float z = acc[mt][nt][reg] + bcol[nt];
        float y = (z - mean)*inv*gcol[nt] + becol[nt];
        y = fmaxf(y, 0.f);
        short hh, mm2, ll;
        split3f(y, hh, mm2, ll);
        size_t o = (size_t)(r0 + row)*256 + (wave*4 + nt)*16 + l15;
        hp[o]             = (unsigned short)hh;
        hp[2097152 + o]   = (unsigned short)mm2;
        hp[2*2097152 + o] = (unsigned short)ll;
      }
    }
}

// ---------------- kernel 2: feats = relu(LN(h @ W2 + b2)), MFMA 6-pass ----
// Tile 32 rows x 512 cols, K=256. 4 waves x 128 cols. A pre-split by rp1.
__global__ __launch_bounds__(256) void k_rp2_mfma(const unsigned short* __restrict__ hp,
    const unsigned short* __restrict__ w2p, const float* __restrict__ bias,
    const float* __restrict__ g, const float* __restrict__ beta,
    float* __restrict__ feats)
{
  __shared__ unsigned short xs[3*32*256];   // 48 KB
  __shared__ float part[4][32][2];
  const int tid = threadIdx.x;
  const int r0  = blockIdx.x * 32;
  for (int i = tid; i < 3*32*32; i += 256){
    int p = i >> 10, rem = i & 1023, r = rem >> 5, gg = rem & 31;
    const unsigned short* sp = hp + (size_t)p*2097152 + (size_t)(r0+r)*256 + gg*8;
    short8 v = *(const short8*)sp;
    *(short8*)(xs + (p*32 + r)*256 + ((gg ^ (r & 7)) << 3)) = v;
  }
  __syncthreads();
  const int wave = tid >> 6, lane = tid & 63, lquad = lane >> 4, l15 = lane & 15;
  f32x4 acc[2][8];
  #pragma unroll
  for (int mt = 0; mt < 2; mt++)
    #pragma unroll
    for (int nt = 0; nt < 8; nt++) acc[mt][nt] = (f32x4){0.f,0.f,0.f,0.f};

  const int pstride = 256*512;
  for (int ks4 = 0; ks4 < 8; ks4++){
    short8 ah[2], am[2], al[2];
    #pragma unroll
    for (int mt = 0; mt < 2; mt++){
      int r = mt*16 + l15;
      int goff = (((ks4*4 + lquad) ^ (r & 7)) << 3);
      ah[mt] = *(const short8*)(xs + (0*32 + r)*256 + goff);
      am[mt] = *(const short8*)(xs + (1*32 + r)*256 + goff);
      al[mt] = *(const short8*)(xs + (2*32 + r)*256 + goff);
    }
    #pragma unroll
    for (int nt = 0; nt < 8; nt++){
      int ntg = wave*8 + nt;
      const unsigned short* bp = w2p + (size_t)(((ntg*8 + ks4)*64 + lane)*8);
      short8 bh = *(const short8*)bp;
      short8 bm = *(const short8*)(bp + pstride);
      short8 bl = *(const short8*)(bp + 2*pstride);
      #pragma unroll
      for (int mt = 0; mt < 2; mt++)
        acc[mt][nt] = mfma6(ah[mt], am[mt], al[mt], bh, bm, bl, acc[mt][nt]);
    }
  }

  float bcol[8], gcol[8], becol[8];
  #pragma unroll
  for (int nt = 0; nt < 8; nt++){
    int col = (wave*8 + nt)*16 + l15;
    bcol[nt] = bias[col]; gcol[nt] = g[col]; becol[nt] = beta[col];
  }
  #pragma unroll
  for (int mt = 0; mt < 2; mt++)
    #pragma unroll
    for (int reg = 0; reg < 4; reg++){
      float s = 0.f, q = 0.f;
      #pragma unroll
      for (int nt = 0; nt < 8; nt++){
        float z = acc[mt][nt][reg] + bcol[nt];
        s += z; q += z*z;
      }
      #pragma unroll
      for (int o = 1; o < 16; o <<= 1){ s += __shfl_xor(s, o, 64); q += __shfl_xor(q, o, 64); }
      int row = mt*16 + lquad*4 + reg;
      if (l15 == 0){ part[wave][row][0] = s; part[wave][row][1] = q; }
    }
  __syncthreads();
  #pragma unroll
  for (int mt = 0; mt < 2; mt++)
    #pragma unroll
    for (int reg = 0; reg < 4; reg++){
      int row = mt*16 + lquad*4 + reg;
      float s = part[0][row][0] + part[1][row][0] + part[2][row][0] + part[3][row][0];
      float q = part[0][row][1] + part[1][row][1] + part[2][row][1] + part[3][row][1];
      float mean = s * (1.0f/512.0f);
      float var  = q * (1.0f/512.0f) - mean*mean;
      float inv  = 1.0f / sqrtf(var + EPSv);
      #pragma unroll
      for (int nt = 0; nt < 8; nt++){
        float z = acc[mt][nt][reg] + bcol[nt];
        float y = (z - mean)*inv*gcol[nt] + becol[nt];
        feats[(size_t)(r0 + row)*512 + (wave*8 + nt)*16 + l15] = fmaxf(y, 0.f);
      }
    }
}

// ---------------- kernel 3: logits -> softmax -> top3 + per-expert lists
__global__ __launch_bounds__(256) void k_gate(const float* __restrict__ F,
    const float* __restrict__ W, const float* __restrict__ bop,
    float* __restrict__ dout, int* __restrict__ cnt, int* __restrict__ list)
{
  __shared__ float fs[8][512];
  __shared__ float part[4][8][64];
  __shared__ float lg[8][64];
  const int tid = threadIdx.x;
  const int r0  = blockIdx.x * 8;
  for (int i = tid; i < 8*128; i += 256){
    int r = i >> 7, c = i & 127;
    ((float4*)fs[r])[c] = ((const float4*)F)[(size_t)(r0+r)*128 + c];
  }
  __syncthreads();
  const int col = tid & 63, seg = tid >> 6;
  float acc[8] = {0,0,0,0,0,0,0,0};
  const int kbase = seg * 128;
  for (int k = kbase; k < kbase + 128; k++){
    float w = W[k*64 + col];
    #pragma unroll
    for (int r = 0; r < 8; r++) acc[r] += fs[r][k] * w;
  }
  #pragma unroll
  for (int r = 0; r < 8; r++) part[seg][r][col] = acc[r];
  __syncthreads();
  for (int i = tid; i < 8*64; i += 256){
    int r = i >> 6, c = i & 63;
    lg[r][c] = part[0][r][c] + part[1][r][c] + part[2][r][c] + part[3][r][c] + bop[c];
  }
  __syncthreads();
  const int wave = tid >> 6, lane = tid & 63;
  for (int rr = 0; rr < 2; rr++){
    int r = wave*2 + rr, row = r0 + r;
    float l = lg[r][lane];
    float mx = l;
    #pragma unroll
    for (int o = 32; o; o >>= 1) mx = fmaxf(mx, __shfl_xor(mx, o, 64));
    float p = expf(l - mx);
    float s = wave_sum64(p);
    p /= s;
    float pv = p;
    for (int j = 0; j < 3; j++){
      float v = pv; int idx = lane;
      #pragma unroll
      for (int o = 32; o; o >>= 1){
        float ov = __shfl_xor(v, o, 64);
        int   oi = __shfl_xor(idx, o, 64);
        if (ov > v || (ov == v && oi < idx)){ v = ov; idx = oi; }
      }
      if (lane == 0){
        dout[(size_t)row*3 + j]                 = v;
        dout[(size_t)Bv*3 + (size_t)row*3 + j]  = (float)idx;
      }
      if (v >= CONFv){
        if (lane == 0){
          int pos = atomicAdd(&cnt[idx], 1);
          list[idx*Bv + pos] = (row << 2) | j;
        }
      } else {
        if (lane < 16) dout[(size_t)Bv*6 + (size_t)row*48 + j*16 + lane] = 0.f;
      }
      if (lane == idx) pv = -1.0f;
    }
  }
}

// ---------------- kernel 3.5: build compacted (expert, tile32) work list ----
__global__ void k_sched(const int* __restrict__ cnt, int* __restrict__ work,
                        int* __restrict__ ntl)
{
  __shared__ int base[64];
  if (threadIdx.x == 0){
    int s = 0;
    for (int e = 0; e < 64; e++){ base[e] = s; s += (cnt[e] + 31) >> 5; }
    *ntl = s;
  }
  __syncthreads();
  int e  = threadIdx.x;
  int nt = (cnt[e] + 31) >> 5;
  int b0 = base[e];
  for (int t = 0; t < nt; t++) work[b0 + t] = (e << 16) | t;
}

// ---------------- kernel 4: expert MLP, split-bf16 3-pass MFMA GEMM1 -------
__global__ __launch_bounds__(256) void k_expert(const float* __restrict__ F,
    const float* __restrict__ W1, const float* __restrict__ b1,
    const float* __restrict__ g,  const float* __restrict__ beta,
    const float* __restrict__ W2, const float* __restrict__ b2,
    const int* __restrict__ cnt,  const int* __restrict__ list,
    const int* __restrict__ work, const int* __restrict__ ntiles,
    float* __restrict__ dout)
{
  extern __shared__ unsigned char smem[];          // 65536 B dynamic
  unsigned short* xh = (unsigned short*)smem;      // [32][512] bf16-hi (swizzled)
  unsigned short* xl = xh + 32*512;                // [32][512] bf16-lo
  float* zs = (float*)smem;                        // [32][265] overlay after GEMM1

  if ((int)blockIdx.x >= *ntiles) return;
  const int desc = work[blockIdx.x];
  const int e = desc >> 16, t = desc & 0xffff;
  const int n = cnt[e];
  const int base = t * 32;
  const int m = min(32, n - base);
  const int* lrow = list + e*Bv + base;
  const int tid = threadIdx.x;

  for (int i = tid; i < 32*128; i += 256){
    int r = i >> 7, c4 = i & 127;
    int ev = lrow[(r < m) ? r : 0];
    int row = ev >> 2;
    float4 v = ((const float4*)(F + (size_t)row*512))[c4];
    unsigned u0 = __float_as_uint(v.x), u1 = __float_as_uint(v.y);
    unsigned u2 = __float_as_uint(v.z), u3 = __float_as_uint(v.w);
    float l0f = v.x - __uint_as_float(u0 & 0xffff0000u);
    float l1f = v.y - __uint_as_float(u1 & 0xffff0000u);
    float l2f = v.z - __uint_as_float(u2 & 0xffff0000u);
    float l3f = v.w - __uint_as_float(u3 & 0xffff0000u);
    unsigned hpack0 = (u0 >> 16) | (u1 & 0xffff0000u);
    unsigned hpack1 = (u2 >> 16) | (u3 & 0xffff0000u);
    unsigned lpack0 = (__float_as_uint(l0f) >> 16) | (__float_as_uint(l1f) & 0xffff0000u);
    unsigned lpack1 = (__float_as_uint(l2f) >> 16) | (__float_as_uint(l3f) & 0xffff0000u);
    int gidx = c4 >> 1, half = c4 & 1;
    int off = r*512 + ((gidx ^ (r & 7)) << 3) + half*4;
    ((unsigned*)(xh + off))[0] = hpack0;
    ((unsigned*)(xh + off))[1] = hpack1;
    ((unsigned*)(xl + off))[0] = lpack0;
    ((unsigned*)(xl + off))[1] = lpack1;
  }
  __syncthreads();

  const int wave = tid >> 6, lane = tid & 63;
  const int lquad = lane >> 4, l15 = lane & 15;
  const float* W1e = W1 + (size_t)e * 512 * 256;
  const int colbase = wave * 64;

  f32x4 acc[2][4];
  #pragma unroll
  for (int mt = 0; mt < 2; mt++)
    #pragma unroll
    for (int nt = 0; nt < 4; nt++)
      acc[mt][nt] = (f32x4){0.f, 0.f, 0.f, 0.f};

  for (int ks = 0; ks < 512; ks += 32){
    short8 ah[2], al[2];
    int gk = (ks >> 3) + lquad;
    #pragma unroll
    for (int mt = 0; mt < 2; mt++){
      int r = mt*16 + l15;
      int off = r*512 + ((gk ^ (r & 7)) << 3);
      ah[mt] = *(const short8*)(xh + off);
      al[mt] = *(const short8*)(xl + off);
    }
    #pragma unroll
    for (int nt = 0; nt < 4; nt++){
      int col = colbase + nt*16 + l15;
      const float* wp = W1e + (size_t)(ks + lquad*8)*256 + col;
      short8 bh, bl;
      #pragma unroll
      for (int j = 0; j < 8; j++){
        float w = wp[(size_t)j*256];
        unsigned u = __float_as_uint(w);
        float lo = w - __uint_as_float(u & 0xffff0000u);
        bh[j] = (short)(u >> 16);
        bl[j] = (short)(__float_as_uint(lo) >> 16);
      }
      #pragma unroll
      for (int mt = 0; mt < 2; mt++){
        acc[mt][nt] = __builtin_amdgcn_mfma_f32_16x16x32_bf16(al[mt], bh, acc[mt][nt], 0, 0, 0);
        acc[mt][nt] = __builtin_amdgcn_mfma_f32_16x16x32_bf16(ah[mt], bl, acc[mt][nt], 0, 0, 0);
        acc[mt][nt] = __builtin_amdgcn_mfma_f32_16x16x32_bf16(ah[mt], bh, acc[mt][nt], 0, 0, 0);
      }
    }
  }
  __syncthreads();

  #pragma unroll
  for (int nt = 0; nt < 4; nt++){
    int col = colbase + nt*16 + l15;
    float bb = b1[e*256 + col];
    #pragma unroll
    for (int mt = 0; mt < 2; mt++)
      #pragma unroll
      for (int rg = 0; rg < 4; rg++){
        int rl = mt*16 + lquad*4 + rg;
        zs[rl*265 + col] = acc[mt][nt][rg] + bb;
      }
  }
  __syncthreads();

  {
    float gv[4], bv[4];
    #pragma unroll
    for (int j = 0; j < 4; j++){
      gv[j] = g[e*256 + lane + 64*j];
      bv[j] = beta[e*256 + lane + 64*j];
    }
    for (int rr = 0; rr < 8; rr++){
      int r = wave*8 + rr;
      float x[4];
      float s = 0.f;
      #pragma unroll
      for (int j = 0; j < 4; j++){ x[j] = zs[r*265 + lane + 64*j]; s += x[j]; }
      s = wave_sum64(s);
      float mm = s * (1.0f/256.0f);
      float v = 0.f;
      #pragma unroll
      for (int j = 0; j < 4; j++){ float d = x[j] - mm; v += d*d; }
      v = wave_sum64(v) * (1.0f/256.0f);
      float inv = 1.0f / sqrtf(v + EPSv);
      #pragma unroll
      for (int j = 0; j < 4; j++){
        float y = (x[j] - mm)*inv*gv[j] + bv[j];
        zs[r*265 + lane + 64*j] = fmaxf(y, 0.f);
      }
    }
  }
  __syncthreads();

  const float* W2e = W2 + (size_t)e * 256 * 16;
  const int r = tid >> 3, pp = (tid & 7) * 2;
  float o0 = b2[e*16 + pp], o1 = b2[e*16 + pp + 1];
  #pragma unroll 8
  for (int c = 0; c < 256; c++){
    float z = zs[r*265 + c];
    float2 w = *(const float2*)(W2e + (size_t)c*16 + pp);
    o0 += z * w.x;
    o1 += z * w.y;
  }
  if (r < m){
    int ev = lrow[r];
    int row = ev >> 2, j = ev & 3;
    float* dst = dout + (size_t)Bv*6 + (size_t)row*48 + j*16 + pp;
    dst[0] = o0;
    dst[1] = o1;
  }
}

extern "C" void kernel_launch(void* const* d_in, const int* in_sizes, int n_in,
                              void* d_out, int out_size, void* d_ws, size_t ws_size,
                              hipStream_t stream)
{
  const float* X   = (const float*)d_in[0];
  const float* w1  = (const float*)d_in[1];
  const float* b1  = (const float*)d_in[2];
  const float* g1  = (const float*)d_in[3];
  const float* be1 = (const float*)d_in[4];
  const float* w2  = (const float*)d_in[5];
  const float* b2  = (const float*)d_in[6];
  const float* g2  = (const float*)d_in[7];
  const float* be2 = (const float*)d_in[8];
  const float* opw = (const float*)d_in[9];
  const float* opb = (const float*)d_in[10];
  const float* pw1 = (const float*)d_in[11];
  const float* pb1 = (const float*)d_in[12];
  const float* pg  = (const float*)d_in[13];
  const float* pbe = (const float*)d_in[14];
  const float* pw2 = (const float*)d_in[15];
  const float* pb2 = (const float*)d_in[16];
  float* out = (float*)d_out;
  char*  ws  = (char*)d_ws;

  // Workspace layout (overlays are ordering-safe on the single stream):
  //   [0, 12MB)    hp: h as 3 bf16 planes (rp1->rp2). list (2MB) overlays @0
  //                (gate writes it AFTER rp2 consumed hp).
  //   [12, 28MB)   feat fp32. w1p (196KB) overlays @12MB (pack1->rp1 consume
  //                it BEFORE rp2 writes feat).
  //   [28, 29MB)   w2p: packed W2 planes (786KB).
  //   [29MB, ...)  cnt/ntl/work.
  unsigned short* hp   = (unsigned short*)ws;
  float*          feat = (float*)(ws + (size_t)12*MB);
  unsigned short* w1p  = (unsigned short*)(ws + (size_t)12*MB);
  unsigned short* w2p  = (unsigned short*)(ws + (size_t)28*MB);
  int*            cnt  = (int*)(ws + (size_t)29*MB);
  int*            ntl  = cnt + 64;
  int*            work = cnt + 128;
  int*            list = (int*)ws;

  k_zero    <<<1,    64, 0, stream>>>(cnt);
  k_packW   <<<128, 256, 0, stream>>>(w1, w1p, 128*256, 8, 4);
  k_packW   <<<512, 256, 0, stream>>>(w2, w2p, 256*512, 9, 8);
  k_rp1_mfma<<<256, 256, 0, stream>>>(X, w1p, b1, g1, be1, hp);
  k_rp2_mfma<<<256, 256, 0, stream>>>(hp, w2p, b2, g2, be2, feat);
  k_gate    <<<1024,256, 0, stream>>>(feat, opw, opb, out, cnt, list);
  k_sched   <<<1,    64, 0, stream>>>(cnt, work, ntl);
  k_expert  <<<832, 256, 65536, stream>>>(feat, pw1, pb1, pg, pbe, pw2, pb2,
                                          cnt, list, work, ntl, out);
}

// Round 4
// 213.268 us; speedup vs baseline: 1.2369x; 1.0365x over previous
//
#include <hip/hip_runtime.h>
#include <math.h>

#define Bv   8192
#define EPSv 1e-5f
#define CONFv 0.1f
#define MB (1024*1024)

typedef __attribute__((ext_vector_type(8))) short short8;
typedef __attribute__((ext_vector_type(4))) float f32x4;

__device__ __forceinline__ float wave_sum64(float v){
  #pragma unroll
  for (int o = 32; o; o >>= 1) v += __shfl_xor(v, o, 64);
  return v;
}

// Truncated 3-way split: x = hi + mid + lo + r, |r| <= 2^-24 |x|.
__device__ __forceinline__ void split3f(float x, short &h, short &m, short &l){
  unsigned u = __float_as_uint(x);
  h = (short)(u >> 16);
  float r1 = x - __uint_as_float(u & 0xffff0000u);
  unsigned u1 = __float_as_uint(r1);
  m = (short)(u1 >> 16);
  float r2 = r1 - __uint_as_float(u1 & 0xffff0000u);
  l = (short)(__float_as_uint(r2) >> 16);
}

__device__ __forceinline__ f32x4 mfma6(short8 ah, short8 am, short8 al,
                                       short8 bh, short8 bm, short8 bl, f32x4 c){
  c = __builtin_amdgcn_mfma_f32_16x16x32_bf16(al, bh, c, 0, 0, 0);
  c = __builtin_amdgcn_mfma_f32_16x16x32_bf16(ah, bl, c, 0, 0, 0);
  c = __builtin_amdgcn_mfma_f32_16x16x32_bf16(am, bm, c, 0, 0, 0);
  c = __builtin_amdgcn_mfma_f32_16x16x32_bf16(am, bh, c, 0, 0, 0);
  c = __builtin_amdgcn_mfma_f32_16x16x32_bf16(ah, bm, c, 0, 0, 0);
  c = __builtin_amdgcn_mfma_f32_16x16x32_bf16(ah, bh, c, 0, 0, 0);
  return c;
}

__device__ __forceinline__ f32x4 mfma3(short8 ah, short8 al,
                                       short8 bh, short8 bl, f32x4 c){
  c = __builtin_amdgcn_mfma_f32_16x16x32_bf16(al, bh, c, 0, 0, 0);
  c = __builtin_amdgcn_mfma_f32_16x16x32_bf16(ah, bl, c, 0, 0, 0);
  c = __builtin_amdgcn_mfma_f32_16x16x32_bf16(ah, bh, c, 0, 0, 0);
  return c;
}

// ---------------- pack expert weights -> hi/lo bf16 B-fragment planes -----
// W1 part (bid<4096): per expert 512x256; idx8 = (((n>>4)*16 + (k>>5))*64 +
//   ((k>>3)&3)*16 + (n&15))*8 + (k&7). hi at ep[idx8], lo at ep[131072+idx8].
// W2 part (bid 4096..4223): per expert 256x16, ktiles=8, single ntile.
// Last block zeroes cnt.
__global__ __launch_bounds__(256) void k_packE(const float* __restrict__ pw1,
    const float* __restrict__ pw2, unsigned short* __restrict__ p1,
    unsigned short* __restrict__ p2, int* __restrict__ cnt)
{
  int bid = blockIdx.x;
  if (bid < 4096){
    int t = bid*256 + threadIdx.x;             // [0, 1048576)
    int e = t >> 14, rem = t & 16383, kg = rem >> 8, n = rem & 255;
    const float* src = pw1 + ((size_t)e << 17) + (size_t)(kg*8)*256 + n;
    short8 h, l;
    #pragma unroll
    for (int j = 0; j < 8; j++){
      float w = src[(size_t)j*256];
      unsigned u = __float_as_uint(w);
      float r2 = w - __uint_as_float(u & 0xffff0000u);
      h[j] = (short)(u >> 16);
      l[j] = (short)(__float_as_uint(r2) >> 16);
    }
    int idx8 = ((((n >> 4)*16 + (kg >> 2))*64) + (kg & 3)*16 + (n & 15)) << 3;
    unsigned short* ep = p1 + (size_t)e * 262144;
    *(short8*)(ep + idx8)          = h;
    *(short8*)(ep + 131072 + idx8) = l;
  } else if (bid < 4224){
    int t = (bid - 4096)*256 + threadIdx.x;    // [0, 32768)
    int e = t >> 9, rem = t & 511, kg = rem >> 4, n = rem & 15;
    const float* src = pw2 + (size_t)e*4096 + (size_t)(kg*8)*16 + n;
    short8 h, l;
    #pragma unroll
    for (int j = 0; j < 8; j++){
      float w = src[(size_t)j*16];
      unsigned u = __float_as_uint(w);
      float r2 = w - __uint_as_float(u & 0xffff0000u);
      h[j] = (short)(u >> 16);
      l[j] = (short)(__float_as_uint(r2) >> 16);
    }
    int idx8 = (((kg >> 2)*64) + (kg & 3)*16 + n) << 3;
    unsigned short* ep = p2 + (size_t)e * 8192;
    *(short8*)(ep + idx8)        = h;
    *(short8*)(ep + 4096 + idx8) = l;
  } else {
    if (threadIdx.x < 64) cnt[threadIdx.x] = 0;
  }
}

// ---------------- pack rp W (K x N fp32) -> 3 bf16 planes, B-frag order ---
__global__ __launch_bounds__(256) void k_packW(const float* __restrict__ W,
    unsigned short* __restrict__ dst, int total, int nlog2, int ktiles)
{
  int gid = blockIdx.x*256 + threadIdx.x;
  if (gid >= total) return;
  int k = gid >> nlog2, n = gid & ((1 << nlog2) - 1);
  short h, m, l;
  split3f(W[gid], h, m, l);
  int idx = (((n >> 4)*ktiles + (k >> 5))*64 + (((k >> 3) & 3)*16 + (n & 15)))*8 + (k & 7);
  dst[idx]           = (unsigned short)h;
  dst[total + idx]   = (unsigned short)m;
  dst[2*total + idx] = (unsigned short)l;
}

// ---------------- kernel 1: h = relu(LN(X @ W1 + b1)), MFMA 6-pass --------
__global__ __launch_bounds__(256) void k_rp1_mfma(const float* __restrict__ X,
    const unsigned short* __restrict__ w1p, const float* __restrict__ bias,
    const float* __restrict__ g, const float* __restrict__ beta,
    unsigned short* __restrict__ hp)
{
  __shared__ float xs[32*128];
  __shared__ float part[4][32][2];
  const int tid = threadIdx.x;
  const int r0  = blockIdx.x * 32;
  for (int i = tid; i < 32*32; i += 256){
    int r = i >> 5, c4 = i & 31;
    float4 v = ((const float4*)X)[(size_t)(r0+r)*32 + c4];
    int off = r*128 + (((c4 >> 1) ^ (r & 7)) << 3) + ((c4 & 1) << 2);
    *(float4*)(xs + off) = v;
  }
  __syncthreads();
  const int wave = tid >> 6, lane = tid & 63, lquad = lane >> 4, l15 = lane & 15;
  f32x4 acc[2][4];
  #pragma unroll
  for (int mt = 0; mt < 2; mt++)
    #pragma unroll
    for (int nt = 0; nt < 4; nt++) acc[mt][nt] = (f32x4){0.f,0.f,0.f,0.f};

  const int pstride = 128*256;
  for (int ks4 = 0; ks4 < 4; ks4++){
    short8 ah[2], am[2], al[2];
    #pragma unroll
    for (int mt = 0; mt < 2; mt++){
      int r = mt*16 + l15;
      const float* ap = xs + r*128 + (((ks4*4 + lquad) ^ (r & 7)) << 3);
      float4 a0 = *(const float4*)ap;
      float4 a1 = *(const float4*)(ap + 4);
      float av[8] = {a0.x,a0.y,a0.z,a0.w,a1.x,a1.y,a1.z,a1.w};
      #pragma unroll
      for (int j = 0; j < 8; j++){
        short hh, mm2, ll;
        split3f(av[j], hh, mm2, ll);
        ah[mt][j] = hh; am[mt][j] = mm2; al[mt][j] = ll;
      }
    }
    #pragma unroll
    for (int nt = 0; nt < 4; nt++){
      int ntg = wave*4 + nt;
      const unsigned short* bp = w1p + (size_t)(((ntg*4 + ks4)*64 + lane)*8);
      short8 bh = *(const short8*)bp;
      short8 bm = *(const short8*)(bp + pstride);
      short8 bl = *(const short8*)(bp + 2*pstride);
      #pragma unroll
      for (int mt = 0; mt < 2; mt++)
        acc[mt][nt] = mfma6(ah[mt], am[mt], al[mt], bh, bm, bl, acc[mt][nt]);
    }
  }

  float bcol[4], gcol[4], becol[4];
  #pragma unroll
  for (int nt = 0; nt < 4; nt++){
    int col = (wave*4 + nt)*16 + l15;
    bcol[nt] = bias[col]; gcol[nt] = g[col]; becol[nt] = beta[col];
  }
  #pragma unroll
  for (int mt = 0; mt < 2; mt++)
    #pragma unroll
    for (int reg = 0; reg < 4; reg++){
      float s = 0.f, q = 0.f;
      #pragma unroll
      for (int nt = 0; nt < 4; nt++){
        float z = acc[mt][nt][reg] + bcol[nt];
        s += z; q += z*z;
      }
      #pragma unroll
      for (int o = 1; o < 16; o <<= 1){ s += __shfl_xor(s, o, 64); q += __shfl_xor(q, o, 64); }
      int row = mt*16 + lquad*4 + reg;
      if (l15 == 0){ part[wave][row][0] = s; part[wave][row][1] = q; }
    }
  __syncthreads();
  #pragma unroll
  for (int mt = 0; mt < 2; mt++)
    #pragma unroll
    for (int reg = 0; reg < 4; reg++){
      int row = mt*16 + lquad*4 + reg;
      float s = part[0][row][0] + part[1][row][0] + part[2][row][0] + part[3][row][0];
      float q = part[0][row][1] + part[1][row][1] + part[2][row][1] + part[3][row][1];
      float mean = s * (1.0f/256.0f);
      float var  = q * (1.0f/256.0f) - mean*mean;
      float inv  = 1.0f / sqrtf(var + EPSv);
      #pragma unroll
      for (int nt = 0; nt < 4; nt++){
        float z = acc[mt][nt][reg] + bcol[nt];
        float y = (z - mean)*inv*gcol[nt] + becol[nt];
        y = fmaxf(y, 0.f);
        short hh, mm2, ll;
        split3f(y, hh, mm2, ll);
        size_t o = (size_t)(r0 + row)*256 + (wave*4 + nt)*16 + l15;
        hp[o]             = (unsigned short)hh;
        hp[2097152 + o]   = (unsigned short)mm2;
        hp[2*2097152 + o] = (unsigned short)ll;
      }
    }
}

// ---------------- kernel 2: feats = relu(LN(h @ W2 + b2)), MFMA 6-pass ----
__global__ __launch_bounds__(256) void k_rp2_mfma(const unsigned short* __restrict__ hp,
    const unsigned short* __restrict__ w2p, const float* __restrict__ bias,
    const float* __restrict__ g, const float* __restrict__ beta,
    float* __restrict__ feats)
{
  __shared__ unsigned short xs[3*32*256];   // 48 KB
  __shared__ float part[4][32][2];
  const int tid = threadIdx.x;
  const int r0  = blockIdx.x * 32;
  for (int i = tid; i < 3*32*32; i += 256){
    int p = i >> 10, rem = i & 1023, r = rem >> 5, gg = rem & 31;
    const unsigned short* sp = hp + (size_t)p*2097152 + (size_t)(r0+r)*256 + gg*8;
    short8 v = *(const short8*)sp;
    *(short8*)(xs + (p*32 + r)*256 + ((gg ^ (r & 7)) << 3)) = v;
  }
  __syncthreads();
  const int wave = tid >> 6, lane = tid & 63, lquad = lane >> 4, l15 = lane & 15;
  f32x4 acc[2][8];
  #pragma unroll
  for (int mt = 0; mt < 2; mt++)
    #pragma unroll
    for (int nt = 0; nt < 8; nt++) acc[mt][nt] = (f32x4){0.f,0.f,0.f,0.f};

  const int pstride = 256*512;
  for (int ks4 = 0; ks4 < 8; ks4++){
    short8 ah[2], am[2], al[2];
    #pragma unroll
    for (int mt = 0; mt < 2; mt++){
      int r = mt*16 + l15;
      int goff = (((ks4*4 + lquad) ^ (r & 7)) << 3);
      ah[mt] = *(const short8*)(xs + (0*32 + r)*256 + goff);
      am[mt] = *(const short8*)(xs + (1*32 + r)*256 + goff);
      al[mt] = *(const short8*)(xs + (2*32 + r)*256 + goff);
    }
    #pragma unroll
    for (int nt = 0; nt < 8; nt++){
      int ntg = wave*8 + nt;
      const unsigned short* bp = w2p + (size_t)(((ntg*8 + ks4)*64 + lane)*8);
      short8 bh = *(const short8*)bp;
      short8 bm = *(const short8*)(bp + pstride);
      short8 bl = *(const short8*)(bp + 2*pstride);
      #pragma unroll
      for (int mt = 0; mt < 2; mt++)
        acc[mt][nt] = mfma6(ah[mt], am[mt], al[mt], bh, bm, bl, acc[mt][nt]);
    }
  }

  float bcol[8], gcol[8], becol[8];
  #pragma unroll
  for (int nt = 0; nt < 8; nt++){
    int col = (wave*8 + nt)*16 + l15;
    bcol[nt] = bias[col]; gcol[nt] = g[col]; becol[nt] = beta[col];
  }
  #pragma unroll
  for (int mt = 0; mt < 2; mt++)
    #pragma unroll
    for (int reg = 0; reg < 4; reg++){
      float s = 0.f, q = 0.f;
      #pragma unroll
      for (int nt = 0; nt < 8; nt++){
        float z = acc[mt][nt][reg] + bcol[nt];
        s += z; q += z*z;
      }
      #pragma unroll
      for (int o = 1; o < 16; o <<= 1){ s += __shfl_xor(s, o, 64); q += __shfl_xor(q, o, 64); }
      int row = mt*16 + lquad*4 + reg;
      if (l15 == 0){ part[wave][row][0] = s; part[wave][row][1] = q; }
    }
  __syncthreads();
  #pragma unroll
  for (int mt = 0; mt < 2; mt++)
    #pragma unroll
    for (int reg = 0; reg < 4; reg++){
      int row = mt*16 + lquad*4 + reg;
      float s = part[0][row][0] + part[1][row][0] + part[2][row][0] + part[3][row][0];
      float q = part[0][row][1] + part[1][row][1] + part[2][row][1] + part[3][row][1];
      float mean = s * (1.0f/512.0f);
      float var  = q * (1.0f/512.0f) - mean*mean;
      float inv  = 1.0f / sqrtf(var + EPSv);
      #pragma unroll
      for (int nt = 0; nt < 8; nt++){
        float z = acc[mt][nt][reg] + bcol[nt];
        float y = (z - mean)*inv*gcol[nt] + becol[nt];
        feats[(size_t)(r0 + row)*512 + (wave*8 + nt)*16 + l15] = fmaxf(y, 0.f);
      }
    }
}

// ---------------- kernel 3: logits -> softmax -> top3 + per-expert lists
__global__ __launch_bounds__(256) void k_gate(const float* __restrict__ F,
    const float* __restrict__ W, const float* __restrict__ bop,
    float* __restrict__ dout, int* __restrict__ cnt, int* __restrict__ list)
{
  __shared__ float fs[8][512];
  __shared__ float part[4][8][64];
  __shared__ float lg[8][64];
  const int tid = threadIdx.x;
  const int r0  = blockIdx.x * 8;
  for (int i = tid; i < 8*128; i += 256){
    int r = i >> 7, c = i & 127;
    ((float4*)fs[r])[c] = ((const float4*)F)[(size_t)(r0+r)*128 + c];
  }
  __syncthreads();
  const int col = tid & 63, seg = tid >> 6;
  float acc[8] = {0,0,0,0,0,0,0,0};
  const int kbase = seg * 128;
  for (int k = kbase; k < kbase + 128; k++){
    float w = W[k*64 + col];
    #pragma unroll
    for (int r = 0; r < 8; r++) acc[r] += fs[r][k] * w;
  }
  #pragma unroll
  for (int r = 0; r < 8; r++) part[seg][r][col] = acc[r];
  __syncthreads();
  for (int i = tid; i < 8*64; i += 256){
    int r = i >> 6, c = i & 63;
    lg[r][c] = part[0][r][c] + part[1][r][c] + part[2][r][c] + part[3][r][c] + bop[c];
  }
  __syncthreads();
  const int wave = tid >> 6, lane = tid & 63;
  for (int rr = 0; rr < 2; rr++){
    int r = wave*2 + rr, row = r0 + r;
    float l = lg[r][lane];
    float mx = l;
    #pragma unroll
    for (int o = 32; o; o >>= 1) mx = fmaxf(mx, __shfl_xor(mx, o, 64));
    float p = expf(l - mx);
    float s = wave_sum64(p);
    p /= s;
    float pv = p;
    for (int j = 0; j < 3; j++){
      float v = pv; int idx = lane;
      #pragma unroll
      for (int o = 32; o; o >>= 1){
        float ov = __shfl_xor(v, o, 64);
        int   oi = __shfl_xor(idx, o, 64);
        if (ov > v || (ov == v && oi < idx)){ v = ov; idx = oi; }
      }
      if (lane == 0){
        dout[(size_t)row*3 + j]                 = v;
        dout[(size_t)Bv*3 + (size_t)row*3 + j]  = (float)idx;
      }
      if (v >= CONFv){
        if (lane == 0){
          int pos = atomicAdd(&cnt[idx], 1);
          list[idx*Bv + pos] = (row << 2) | j;
        }
      } else {
        if (lane < 16) dout[(size_t)Bv*6 + (size_t)row*48 + j*16 + lane] = 0.f;
      }
      if (lane == idx) pv = -1.0f;
    }
  }
}

// ---------------- kernel 4: expert MLP, packed-B MFMA ---------------------
// (e,t) derived in-block from cnt via wave prefix-scan; tiles XCD-swizzled.
__global__ __launch_bounds__(256) void k_expert(const float* __restrict__ F,
    const unsigned short* __restrict__ p1, const float* __restrict__ b1,
    const float* __restrict__ g,  const float* __restrict__ beta,
    const unsigned short* __restrict__ p2, const float* __restrict__ b2,
    const int* __restrict__ cnt,  const int* __restrict__ list,
    float* __restrict__ dout)
{
  extern __shared__ unsigned char smem[];          // 65536 B dynamic
  unsigned short* xh = (unsigned short*)smem;      // [32][512] bf16-hi (swizzled)
  unsigned short* xl = xh + 32*512;                // [32][512] bf16-lo
  float*          zs = (float*)smem;               // [32][264] fp32 overlay
  unsigned short* zp = (unsigned short*)smem;      // z planes: row stride 528,
                                                   // hi at [0,264), lo at [264,528)
  __shared__ int sdesc[3];                         // e, t, n (valid flag via e<0)

  const int tid = threadIdx.x;
  const int wave = tid >> 6, lane = tid & 63;
  const int lquad = lane >> 4, l15 = lane & 15;

  if (wave == 0){
    int c  = cnt[lane];
    int tl = (c + 31) >> 5;
    int incl = tl;
    #pragma unroll
    for (int o = 1; o < 64; o <<= 1){
      int v = __shfl_up(incl, o, 64);
      if (lane >= o) incl += v;
    }
    int total = __shfl(incl, 63, 64);
    int G   = (total + 7) >> 3;                 // tiles per XCD group
    int grp = blockIdx.x & 7, rr = blockIdx.x >> 3;
    int lgc = grp*G + rr;                        // logical tile index
    int ok  = (G > 0) && (rr < G) && (lgc < total);
    unsigned long long bm = __ballot(ok && (incl > lgc));
    if (lane == 0){
      if (!ok || bm == 0ull){ sdesc[0] = -1; }
      else {
        int e = __ffsll((long long)bm) - 1;
        sdesc[0] = e; sdesc[1] = lgc; sdesc[2] = 0;
      }
    }
    if (bm != 0ull && ok){
      int e = __ffsll((long long)bm) - 1;
      int excl = __shfl(incl - tl, e, 64);
      int ne   = __shfl(c, e, 64);
      if (lane == 0){ sdesc[1] = lgc - excl; sdesc[2] = ne; }
    }
  }
  __syncthreads();
  const int e = sdesc[0];
  if (e < 0) return;
  const int t = sdesc[1];
  const int n = sdesc[2];
  const int base = t * 32;
  const int m = min(32, n - base);
  const int* lrow = list + e*Bv + base;

  // ---- stage features -> hi/lo bf16 planes (swizzled 8-short groups)
  for (int i = tid; i < 32*128; i += 256){
    int r = i >> 7, c4 = i & 127;
    int ev = lrow[(r < m) ? r : 0];
    int row = ev >> 2;
    float4 v = ((const float4*)(F + (size_t)row*512))[c4];
    unsigned u0 = __float_as_uint(v.x), u1 = __float_as_uint(v.y);
    unsigned u2 = __float_as_uint(v.z), u3 = __float_as_uint(v.w);
    float l0f = v.x - __uint_as_float(u0 & 0xffff0000u);
    float l1f = v.y - __uint_as_float(u1 & 0xffff0000u);
    float l2f = v.z - __uint_as_float(u2 & 0xffff0000u);
    float l3f = v.w - __uint_as_float(u3 & 0xffff0000u);
    unsigned hpack0 = (u0 >> 16) | (u1 & 0xffff0000u);
    unsigned hpack1 = (u2 >> 16) | (u3 & 0xffff0000u);
    unsigned lpack0 = (__float_as_uint(l0f) >> 16) | (__float_as_uint(l1f) & 0xffff0000u);
    unsigned lpack1 = (__float_as_uint(l2f) >> 16) | (__float_as_uint(l3f) & 0xffff0000u);
    int gidx = c4 >> 1, half = c4 & 1;
    int off = r*512 + ((gidx ^ (r & 7)) << 3) + half*4;
    ((unsigned*)(xh + off))[0] = hpack0;
    ((unsigned*)(xh + off))[1] = hpack1;
    ((unsigned*)(xl + off))[0] = lpack0;
    ((unsigned*)(xl + off))[1] = lpack1;
  }
  __syncthreads();

  // ---- GEMM1: 32x256, K=512, packed-B 3-pass MFMA
  const unsigned short* p1e = p1 + (size_t)e * 262144;
  const int colbase = wave * 64;
  f32x4 acc[2][4];
  #pragma unroll
  for (int mt = 0; mt < 2; mt++)
    #pragma unroll
    for (int nt = 0; nt < 4; nt++) acc[mt][nt] = (f32x4){0.f,0.f,0.f,0.f};

  for (int kt = 0; kt < 16; kt++){
    short8 ah[2], al[2];
    int gk = kt*4 + lquad;
    #pragma unroll
    for (int mt = 0; mt < 2; mt++){
      int r = mt*16 + l15;
      int off = r*512 + ((gk ^ (r & 7)) << 3);
      ah[mt] = *(const short8*)(xh + off);
      al[mt] = *(const short8*)(xl + off);
    }
    #pragma unroll
    for (int nt = 0; nt < 4; nt++){
      int ntg = wave*4 + nt;
      const unsigned short* bp = p1e + (((ntg*16 + kt)*64 + lane) << 3);
      short8 bh = *(const short8*)bp;
      short8 bl = *(const short8*)(bp + 131072);
      #pragma unroll
      for (int mt = 0; mt < 2; mt++)
        acc[mt][nt] = mfma3(ah[mt], al[mt], bh, bl, acc[mt][nt]);
    }
  }
  __syncthreads();   // x planes dead; zs overlays

  // ---- z = acc + b1 (fp32, row stride 264 floats)
  #pragma unroll
  for (int nt = 0; nt < 4; nt++){
    int col = colbase + nt*16 + l15;
    float bb = b1[e*256 + col];
    #pragma unroll
    for (int mt = 0; mt < 2; mt++)
      #pragma unroll
      for (int rg = 0; rg < 4; rg++){
        int rl = mt*16 + lquad*4 + rg;
        zs[rl*264 + col] = acc[mt][nt][rg] + bb;
      }
  }
  __syncthreads();

  // ---- LN + ReLU; write z back in place as hi/lo bf16 planes (wave-local rows)
  {
    float gv[4], bv[4];
    #pragma unroll
    for (int j = 0; j < 4; j++){
      gv[j] = g[e*256 + lane + 64*j];
      bv[j] = beta[e*256 + lane + 64*j];
    }
    for (int rr2 = 0; rr2 < 8; rr2++){
      int r = wave*8 + rr2;
      float x[4];
      float s = 0.f;
      #pragma unroll
      for (int j = 0; j < 4; j++){ x[j] = zs[r*264 + lane + 64*j]; s += x[j]; }
      s = wave_sum64(s);
      float mm = s * (1.0f/256.0f);
      float v = 0.f;
      #pragma unroll
      for (int j = 0; j < 4; j++){ float d = x[j] - mm; v += d*d; }
      v = wave_sum64(v) * (1.0f/256.0f);
      float inv = 1.0f / sqrtf(v + EPSv);
      #pragma unroll
      for (int j = 0; j < 4; j++){
        int c = lane + 64*j;
        float y = fmaxf((x[j] - mm)*inv*gv[j] + bv[j], 0.f);
        unsigned u = __float_as_uint(y);
        float res = y - __uint_as_float(u & 0xffff0000u);
        zp[r*528 + c]       = (unsigned short)(u >> 16);
        zp[r*528 + 264 + c] = (unsigned short)(__float_as_uint(res) >> 16);
      }
    }
  }
  __syncthreads();

  // ---- GEMM2: 32x16, K=256, 3-pass MFMA; waves 0,1 handle 16 rows each
  if (wave < 2){
    const unsigned short* p2e = p2 + (size_t)e * 8192;
    f32x4 acc2 = (f32x4){0.f,0.f,0.f,0.f};
    for (int kt2 = 0; kt2 < 8; kt2++){
      const unsigned short* zb = zp + (wave*16 + l15)*528 + kt2*32 + lquad*8;
      short8 ahh = *(const short8*)zb;
      short8 all2 = *(const short8*)(zb + 264);
      const unsigned short* bp = p2e + ((kt2*64 + lane) << 3);
      short8 bh = *(const short8*)bp;
      short8 bl = *(const short8*)(bp + 4096);
      acc2 = mfma3(ahh, all2, bh, bl, acc2);
    }
    float b2v = b2[e*16 + l15];
    #pragma unroll
    for (int reg = 0; reg < 4; reg++){
      int rl = wave*16 + lquad*4 + reg;
      if (rl < m){
        int ev = lrow[rl];
        int row = ev >> 2, j = ev & 3;
        dout[(size_t)Bv*6 + (size_t)row*48 + j*16 + l15] = acc2[reg] + b2v;
      }
    }
  }
}

extern "C" void kernel_launch(void* const* d_in, const int* in_sizes, int n_in,
                              void* d_out, int out_size, void* d_ws, size_t ws_size,
                              hipStream_t stream)
{
  const float* X   = (const float*)d_in[0];
  const float* w1  = (const float*)d_in[1];
  const float* b1  = (const float*)d_in[2];
  const float* g1  = (const float*)d_in[3];
  const float* be1 = (const float*)d_in[4];
  const float* w2  = (const float*)d_in[5];
  const float* b2  = (const float*)d_in[6];
  const float* g2  = (const float*)d_in[7];
  const float* be2 = (const float*)d_in[8];
  const float* opw = (const float*)d_in[9];
  const float* opb = (const float*)d_in[10];
  const float* pw1 = (const float*)d_in[11];
  const float* pb1 = (const float*)d_in[12];
  const float* pg  = (const float*)d_in[13];
  const float* pbe = (const float*)d_in[14];
  const float* pw2 = (const float*)d_in[15];
  const float* pb2 = (const float*)d_in[16];
  float* out = (float*)d_out;
  char*  ws  = (char*)d_ws;

  // Workspace layout (single-stream ordering makes overlays safe):
  //  [0,32MB)    p1E: packed expert W1 hi/lo planes (persists whole launch)
  //  [32,33MB)   p2E: packed expert W2 hi/lo planes
  //  [33,45MB)   hp: h 3-plane bf16 (packE..rp2); list (2MB) overlays @33MB
  //              (gate writes list after rp2 consumed hp)
  //  [45,61MB)   feat fp32; w1p_rp (196KB) overlays @45MB (consumed by rp1
  //              before rp2 writes feat)
  //  [61,61.75)  w2p_rp packed rp W2 planes
  //  [62MB,..)   cnt
  unsigned short* p1E    = (unsigned short*)ws;
  unsigned short* p2E    = (unsigned short*)(ws + (size_t)32*MB);
  unsigned short* hp     = (unsigned short*)(ws + (size_t)33*MB);
  int*            list   = (int*)(ws + (size_t)33*MB);
  float*          feat   = (float*)(ws + (size_t)45*MB);
  unsigned short* w1p_rp = (unsigned short*)(ws + (size_t)45*MB);
  unsigned short* w2p_rp = (unsigned short*)(ws + (size_t)61*MB);
  int*            cnt    = (int*)(ws + (size_t)62*MB);

  k_packE   <<<4225, 256, 0, stream>>>(pw1, pw2, p1E, p2E, cnt);
  k_packW   <<<128,  256, 0, stream>>>(w1, w1p_rp, 128*256, 8, 4);
  k_packW   <<<512,  256, 0, stream>>>(w2, w2p_rp, 256*512, 9, 8);
  k_rp1_mfma<<<256,  256, 0, stream>>>(X, w1p_rp, b1, g1, be1, hp);
  k_rp2_mfma<<<256,  256, 0, stream>>>(hp, w2p_rp, b2, g2, be2, feat);
  k_gate    <<<1024, 256, 0, stream>>>(feat, opw, opb, out, cnt, list);
  k_expert  <<<832,  256, 65536, stream>>>(feat, p1E, pb1, pg, pbe, p2E, pb2,
                                           cnt, list, out);
}